// Round 19
// baseline (345.495 us; speedup 1.0000x reference)
//
#include <hip/hip_runtime.h>
#include <hip/hip_fp16.h>

#define NG 100000
#define NDR 10000
#define NDI 5000
#define NDOM (3 * NG + NDR + NDI)   // 315000 combined node domain
#define NBUCK 616                   // cdiv(NDOM, 512)
#define BCHUNK 4096                 // emissions per binH block
#define EPT 16                      // emissions per thread (BCHUNK/256)

typedef _Float16 f16x8 __attribute__((ext_vector_type(8)));
typedef float f32x4 __attribute__((ext_vector_type(4)));
typedef float f32x2 __attribute__((ext_vector_type(2)));

__device__ __forceinline__ void atomAddF(float* p, float v) { unsafeAtomicAdd(p, v); }

// fp8 e4m3 (gfx950 OCP) pack/unpack
__device__ __forceinline__ float2 fp8x2_f32(unsigned short v) {
  f32x2 r = __builtin_amdgcn_cvt_pk_f32_fp8((int)v, false);
  return make_float2(r[0], r[1]);
}
__device__ __forceinline__ unsigned char f32_fp8(float v) {
  return (unsigned char)(__builtin_amdgcn_cvt_pk_fp8_f32(v, v, 0, false) & 0xFF);
}

static inline int cdiv_h(int a, int b) { return (a + b - 1) / b; }

// bucket capacity: gene/dst buckets cap 8192; drug-src cap 24576; disease-src cap 32768.
__device__ __host__ __forceinline__ int bcap(int b) {
  return b < 586 ? 8192 : (b < 606 ? 24576 : 32768);
}
__device__ __host__ __forceinline__ int bbase(int b) {
  if (b < 586) return b * 8192;
  if (b < 606) return 586 * 8192 + (b - 586) * 24576;
  return 586 * 8192 + 20 * 24576 + (b - 606) * 32768;
}
#define NPAIR (586 * 8192 + 20 * 24576 + 10 * 32768)

// ---------------- emission decode: idx in [0, Eg+2Ed+2Ec) -> (node, val) ----------------
__device__ __forceinline__ void decode(int idx, const int* __restrict__ ge, int Eg_,
                                       const int* __restrict__ de, int Ed_,
                                       const int* __restrict__ ce, int Ec_,
                                       unsigned& node, unsigned& val) {
  int B1 = Eg_, B2 = Eg_ + Ed_, B3 = Eg_ + 2 * Ed_, B4 = B3 + Ec_;
  if (idx < B1) { node = (unsigned)ge[Eg_ + idx]; val = (unsigned)ge[idx]; }
  else if (idx < B2) { int i = idx - B1; node = NG + (unsigned)de[Ed_ + i]; val = (unsigned)de[i]; }
  else if (idx < B3) { int i = idx - B2; node = 3 * NG + (unsigned)de[i]; val = (unsigned)de[Ed_ + i]; }
  else if (idx < B4) { int i = idx - B3; node = 2 * NG + (unsigned)ce[Ec_ + i]; val = (unsigned)ce[i]; }
  else { int i = idx - B4; node = 3 * NG + NDR + (unsigned)ce[i]; val = (unsigned)ce[Ec_ + i]; }
}

// ---------------- k_build: binH (count-based) || weight prep || watt || colsums ----------------
__global__ __launch_bounds__(256) void k_build(const int* __restrict__ ge, int Eg_,
                                               const int* __restrict__ de, int Ed_,
                                               const int* __restrict__ ce, int Ec_,
                                               int* __restrict__ count616,
                                               unsigned* __restrict__ pairs,
                                               const float* __restrict__ W1,
                                               const float* __restrict__ W2,
                                               const float* __restrict__ Wd,
                                               const float* __restrict__ Wc,
                                               const float* __restrict__ attd_d,
                                               const float* __restrict__ attd_c,
                                               __half* __restrict__ Wt1,
                                               __half* __restrict__ Wt2,
                                               __half* __restrict__ Wtd,
                                               __half* __restrict__ Wtc,
                                               float* __restrict__ watt,
                                               const float* __restrict__ xd,
                                               float* __restrict__ od,
                                               const float* __restrict__ xc,
                                               float* __restrict__ oc) {
  const int ME = Eg_ + 2 * (Ed_ + Ec_);
  const int NBB = (ME + BCHUNK - 1) / BCHUNK;
  int blk = blockIdx.x;
  int t = threadIdx.x;
  if (blk < NBB) {
    __shared__ int hist[NBUCK];
    for (int i = t; i < NBUCK; i += 256) hist[i] = 0;
    __syncthreads();
    int base = blk * BCHUNK;
    int cnt = min(BCHUNK, ME - base);
    unsigned nodeR[EPT], valR[EPT];
#pragma unroll
    for (int k = 0; k < EPT; k++) {
      int j = t + k * 256;
      nodeR[k] = 0xFFFFFFFFu;
      if (j < cnt) decode(base + j, ge, Eg_, de, Ed_, ce, Ec_, nodeR[k], valR[k]);
    }
#pragma unroll
    for (int k = 0; k < EPT; k++)
      if (nodeR[k] != 0xFFFFFFFFu) atomicAdd(&hist[nodeR[k] >> 9], 1);
    __syncthreads();
    for (int b = t; b < NBUCK; b += 256) {
      int h = hist[b];
      hist[b] = h ? (bbase(b) + atomicAdd(&count616[b], h)) : 0;
    }
    __syncthreads();
#pragma unroll
    for (int k = 0; k < EPT; k++) {
      if (nodeR[k] == 0xFFFFFFFFu) continue;
      unsigned b = nodeR[k] >> 9;
      int p = atomicAdd(&hist[b], 1);
      if (p < bbase(b) + bcap(b))                           // OOB guard
        pairs[p] = ((nodeR[k] - (b << 9)) << 17) | valR[k]; // local(9b) | val(17b)
    }
    return;
  }
  int fb = blk - NBB;
  if (fb < 40) {
    __shared__ float tile[64][65];
    const float* W;
    __half* Wt;
    int N, k0, n0;
    if (fb < 4) { W = W1; Wt = Wt1; N = 128; k0 = (fb >> 1) * 64; n0 = (fb & 1) * 64; }
    else if (fb < 8) { int b = fb - 4; W = W2; Wt = Wt2; N = 128; k0 = (b >> 1) * 64; n0 = (b & 1) * 64; }
    else if (fb < 24) { int b = fb - 8; W = Wd; Wt = Wtd; N = 512; k0 = (b >> 3) * 64; n0 = (b & 7) * 64; }
    else { int b = fb - 24; W = Wc; Wt = Wtc; N = 512; k0 = (b >> 3) * 64; n0 = (b & 7) * 64; }
    for (int i = t; i < 4096; i += 256) {
      int r = i >> 6, c = i & 63;
      tile[r][c] = W[(size_t)(k0 + r) * N + n0 + c];
    }
    __syncthreads();
    for (int i = t; i < 4096; i += 256) {
      int k = i & 63, n = i >> 6;
      Wt[(size_t)(n0 + n) * 128 + k0 + k] = __float2half(tile[k][n]);
    }
    return;
  }
  if (fb < 44) {
    int slot = (fb - 40) * 256 + t;
    int i = slot >> 3, s8 = slot & 7;
    const float* W = (s8 < 4) ? Wd : Wc;
    const float* A = (s8 < 4) ? attd_d : attd_c;
    int h = s8 & 3;
    float s = 0.f;
    for (int cc = 0; cc < 128; cc++) s += W[(size_t)i * 512 + h * 128 + cc] * A[h * 128 + cc];
    watt[i * 8 + s8] = s;
    return;
  }
  int cb = fb - 44;
  int q = cb >= 79;
  const float* x = q ? xc : xd;
  float* o = q ? oc : od;
  int N = q ? NDI : NDR;
  int r0 = (q ? cb - 79 : cb) * 128 + (t >> 7) * 64;
  int col = t & 127;
  int r1 = min(r0 + 64, N);
  float acc = 0.f;
  for (int r = r0; r < r1; r++) acc += x[(size_t)r * 128 + col];
  if (r0 < N) atomAddF(&o[col], acc);
}

// ---------------- scan616: exclusive prefix over bucket totals (1 block) ----------------
__global__ __launch_bounds__(256) void k_scan616(const int* __restrict__ count616,
                                                 int* __restrict__ bucketbase) {
  __shared__ int s[256];
  int t = threadIdx.x;
  int loc[3];
  int sum = 0;
#pragma unroll
  for (int k = 0; k < 3; k++) {
    int b = 3 * t + k;
    int v = (b < NBUCK) ? min(count616[b], bcap(b)) : 0;
    loc[k] = sum;
    sum += v;
  }
  s[t] = sum;
  __syncthreads();
  for (int off = 1; off < 256; off <<= 1) {
    int add = (t >= off) ? s[t - off] : 0;
    __syncthreads();
    s[t] += add;
    __syncthreads();
  }
  int excl = s[t] - sum;
#pragma unroll
  for (int k = 0; k < 3; k++) {
    int b = 3 * t + k;
    if (b < NBUCK) bucketbase[b] = excl + loc[k];
  }
}

// ---------------- placeAll: per-bucket hist -> node prefix -> rowptr+dis -> place ----------------
__global__ __launch_bounds__(256) void k_placeAll(const int* __restrict__ count616,
                                                  const int* __restrict__ bucketbase,
                                                  const unsigned* __restrict__ pairs,
                                                  int* __restrict__ rowptr,
                                                  float* __restrict__ dis,
                                                  int* __restrict__ adj) {
  __shared__ int hist[512];
  __shared__ int scan[256];
  int b = blockIdx.x;
  int n0 = b << 9;
  int n1 = min(n0 + 512, NDOM);
  int t = threadIdx.x;
  hist[t] = 0;
  hist[t + 256] = 0;
  __syncthreads();
  int base = bbase(b);
  int cnt = min(count616[b], bcap(b));
  for (int i = base + t; i < base + cnt; i += 256) atomicAdd(&hist[pairs[i] >> 17], 1);
  __syncthreads();
  int h0 = hist[2 * t], h1 = hist[2 * t + 1];
  int sum = h0 + h1;
  scan[t] = sum;
  __syncthreads();
  for (int off = 1; off < 256; off <<= 1) {
    int add = (t >= off) ? scan[t - off] : 0;
    __syncthreads();
    scan[t] += add;
    __syncthreads();
  }
  int excl = scan[t] - sum;
  int bb = bucketbase[b];
  int i0 = 2 * t, i1 = 2 * t + 1;
  int r0 = bb + excl, r1 = bb + excl + h0;
  if (n0 + i0 < n1) {
    rowptr[n0 + i0] = r0;
    if (n0 + i0 < NG) dis[n0 + i0] = rsqrtf((float)h0 + 1.0f);
  }
  if (n0 + i1 < n1) {
    rowptr[n0 + i1] = r1;
    if (n0 + i1 < NG) dis[n0 + i1] = rsqrtf((float)h1 + 1.0f);
    if (n0 + i1 == NDOM - 1) rowptr[NDOM] = r1 + h1;
  }
  if (n0 + i0 == NDOM - 1) rowptr[NDOM] = r0 + h0;
  __syncthreads();
  hist[i0] = r0;
  hist[i1] = r1;
  __syncthreads();
  for (int i = base + t; i < base + cnt; i += 256) {
    unsigned pr = pairs[i];
    int p = atomicAdd(&hist[pr >> 17], 1);
    adj[p] = (int)(pr & 0x1FFFFu);
  }
}

// ---------------- MFMA f16 GEMM body: hh[M,128] = (X[M,128] @ W) * dis[row], FP8 out ----------
template <int INF16>
__device__ __forceinline__ void mgemm_body(char* lds, int bx, const void* __restrict__ Xv,
                                           const __half* __restrict__ Wt, int M,
                                           const float* __restrict__ dis,
                                           unsigned char* __restrict__ hh) {
  char* As = lds;              // 64 x 128 f16 = 16 KB
  char* Bs = lds + 16 * 1024;  // 128 x 128 f16 = 32 KB
  const int t = threadIdx.x;
  const int row0 = bx * 64;

#pragma unroll
  for (int rep = 0; rep < 8; rep++) {
    int q = t + rep * 256;
    int r = q >> 4, c16 = (q & 15) * 16;
    uint4 v = *(const uint4*)((const char*)Wt + r * 256 + c16);
    *(uint4*)(Bs + ((r * 256 + c16) ^ ((r & 7) << 4))) = v;
  }
  if (INF16 == 0) {
    const float* X = (const float*)Xv;
#pragma unroll
    for (int rep = 0; rep < 8; rep++) {
      int q = t + rep * 256;
      int r = q >> 5, c4 = (q & 31) * 4;
      int gr = row0 + r;
      float4 xv = make_float4(0.f, 0.f, 0.f, 0.f);
      if (gr < M) xv = *(const float4*)&X[(size_t)gr * 128 + c4];
      __half2 h0 = __floats2half2_rn(xv.x, xv.y);
      __half2 h1 = __floats2half2_rn(xv.z, xv.w);
      uint2 pk;
      pk.x = *(unsigned*)&h0;
      pk.y = *(unsigned*)&h1;
      *(uint2*)(As + ((r * 256 + c4 * 2) ^ ((r & 7) << 4))) = pk;
    }
  } else {
    const __half* X = (const __half*)Xv;
#pragma unroll
    for (int rep = 0; rep < 4; rep++) {
      int q = t + rep * 256;
      int r = q >> 4, c16 = (q & 15) * 16;
      int gr = row0 + r;
      uint4 v = make_uint4(0u, 0u, 0u, 0u);
      if (gr < M) v = *(const uint4*)((const char*)X + (size_t)gr * 256 + c16);
      *(uint4*)(As + ((r * 256 + c16) ^ ((r & 7) << 4))) = v;
    }
  }
  __syncthreads();

  const int w = t >> 6, l = t & 63;
  const int lr = l & 15, lk = l >> 4;
  f32x4 acc[8] = {};
#pragma unroll
  for (int s = 0; s < 4; s++) {
    int arow = w * 16 + lr;
    f16x8 a = *(const f16x8*)(As + ((arow * 256 + lk * 16 + s * 64) ^ ((arow & 7) << 4)));
#pragma unroll
    for (int nt = 0; nt < 8; nt++) {
      int brow = nt * 16 + lr;
      f16x8 b = *(const f16x8*)(Bs + ((brow * 256 + lk * 16 + s * 64) ^ ((brow & 7) << 4)));
      acc[nt] = __builtin_amdgcn_mfma_f32_16x16x32_f16(a, b, acc[nt], 0, 0, 0);
    }
  }
  float ddv[4];
  int rowb = row0 + w * 16 + lk * 4;
#pragma unroll
  for (int j = 0; j < 4; j++) ddv[j] = (rowb + j < M) ? dis[rowb + j] : 0.f;
#pragma unroll
  for (int nt = 0; nt < 8; nt++) {
#pragma unroll
    for (int j = 0; j < 4; j++) {
      int row = rowb + j;
      if (row < M) hh[(size_t)row * 128 + nt * 16 + lr] = f32_fp8(acc[nt][j] * ddv[j]);
    }
  }
}

// ---------------- MFMA f16 GAT GEMM body (bx = row block, h = head) ----------------
__device__ __forceinline__ void mgat_body(char* lds, int bxx, int h,
                                          const float* __restrict__ Xd,
                                          const float* __restrict__ Xc,
                                          const __half* __restrict__ Wtd,
                                          const __half* __restrict__ Wtc,
                                          const float* __restrict__ attSd,
                                          const float* __restrict__ attSc,
                                          __half* __restrict__ hsd,
                                          __half* __restrict__ hsc,
                                          float* __restrict__ a_s_d,
                                          float* __restrict__ a_s_c) {
  char* As = lds;
  char* Bs = lds + 16 * 1024;
  const int t = threadIdx.x;
  const int nbd = (NDR + 63) >> 6;
  const int q = bxx >= nbd;
  const int bx = q ? bxx - nbd : bxx;
  const int M = q ? NDI : NDR;
  const float* X = q ? Xc : Xd;
  const __half* Wt = q ? Wtc : Wtd;
  const float* attS = q ? attSc : attSd;
  __half* hs = q ? hsc : hsd;
  float* a_s = q ? a_s_c : a_s_d;
  const int row0 = bx * 64;
  const __half* Wth = Wt + (size_t)h * 128 * 128;

#pragma unroll
  for (int rep = 0; rep < 8; rep++) {
    int r = (t + rep * 256) >> 4, c16 = ((t + rep * 256) & 15) * 16;
    uint4 v = *(const uint4*)((const char*)Wth + r * 256 + c16);
    *(uint4*)(Bs + ((r * 256 + c16) ^ ((r & 7) << 4))) = v;
  }
#pragma unroll
  for (int rep = 0; rep < 8; rep++) {
    int qq = t + rep * 256;
    int r = qq >> 5, c4 = (qq & 31) * 4;
    int gr = row0 + r;
    float4 xv = make_float4(0.f, 0.f, 0.f, 0.f);
    if (gr < M) xv = *(const float4*)&X[(size_t)gr * 128 + c4];
    __half2 h0 = __floats2half2_rn(xv.x, xv.y);
    __half2 h1 = __floats2half2_rn(xv.z, xv.w);
    uint2 pk;
    pk.x = *(unsigned*)&h0;
    pk.y = *(unsigned*)&h1;
    *(uint2*)(As + ((r * 256 + c4 * 2) ^ ((r & 7) << 4))) = pk;
  }
  __syncthreads();

  const int w = t >> 6, l = t & 63;
  const int lr = l & 15, lk = l >> 4;
  f32x4 acc[8] = {};
#pragma unroll
  for (int s = 0; s < 4; s++) {
    int arow = w * 16 + lr;
    f16x8 a = *(const f16x8*)(As + ((arow * 256 + lk * 16 + s * 64) ^ ((arow & 7) << 4)));
#pragma unroll
    for (int nt = 0; nt < 8; nt++) {
      int brow = nt * 16 + lr;
      f16x8 b = *(const f16x8*)(Bs + ((brow * 256 + lk * 16 + s * 64) ^ ((brow & 7) << 4)));
      acc[nt] = __builtin_amdgcn_mfma_f32_16x16x32_f16(a, b, acc[nt], 0, 0, 0);
    }
  }
  float av[8];
#pragma unroll
  for (int nt = 0; nt < 8; nt++) av[nt] = attS[h * 128 + nt * 16 + lr];

  int rowb = row0 + w * 16 + lk * 4;
  float p[4] = {0.f, 0.f, 0.f, 0.f};
#pragma unroll
  for (int nt = 0; nt < 8; nt++) {
#pragma unroll
    for (int j = 0; j < 4; j++) {
      int row = rowb + j;
      if (row < M) hs[(size_t)row * 512 + h * 128 + nt * 16 + lr] = __float2half(acc[nt][j]);
      p[j] += acc[nt][j] * av[nt];
    }
  }
#pragma unroll
  for (int m = 1; m < 16; m <<= 1) {
#pragma unroll
    for (int j = 0; j < 4; j++) p[j] += __shfl_xor(p[j], m);
  }
  if (lr == 0) {
#pragma unroll
    for (int j = 0; j < 4; j++) {
      int row = rowb + j;
      if (row < M) a_s[(size_t)row * 4 + h] = p[j];
    }
  }
}

// ---------------- fused launch: GCN layer-1 GEMM || GAT source GEMMs ----------------
__global__ __launch_bounds__(256) void k_mm1(const float* __restrict__ X1,
                                             const __half* __restrict__ Wt1,
                                             const float* __restrict__ dis,
                                             unsigned char* __restrict__ hh,
                                             const float* __restrict__ Xd,
                                             const float* __restrict__ Xc,
                                             const __half* __restrict__ Wtd,
                                             const __half* __restrict__ Wtc,
                                             const float* __restrict__ attSd,
                                             const float* __restrict__ attSc,
                                             __half* __restrict__ hsd,
                                             __half* __restrict__ hsc,
                                             float* __restrict__ a_s_d,
                                             float* __restrict__ a_s_c) {
  __shared__ __align__(16) char lds[48 * 1024];
  const int NB1 = (NG + 63) >> 6;
  if ((int)blockIdx.x < NB1) {
    mgemm_body<0>(lds, blockIdx.x, X1, Wt1, NG, dis, hh);
    return;
  }
  int r = blockIdx.x - NB1;
  mgat_body(lds, r >> 2, r & 3, Xd, Xc, Wtd, Wtc, attSd, attSc, hsd, hsc, a_s_d, a_s_c);
}

// ---------------- standalone MFMA GEMM (layer 2, f16 input, fp8 out) ----------------
template <int INF16>
__global__ __launch_bounds__(256) void k_mgemm(const void* __restrict__ Xv,
                                               const __half* __restrict__ Wt, int M,
                                               const float* __restrict__ dis,
                                               unsigned char* __restrict__ hh) {
  __shared__ __align__(16) char lds[48 * 1024];
  mgemm_body<INF16>(lds, blockIdx.x, Xv, Wt, M, dis, hh);
}

// ---------------- GCN aggregation: wave/dst, PAIRED-ROW loads (2 fp8 rows per wave-load) -------
// lanes 0-31 fetch row A, lanes 32-63 row B; 4 fp8 cols/lane; shfl_xor(32) merges halves.
// FIN 1: out = x1 row f16; FIN 2: out = att row (8 scores fp32)
template <int FIN>
__global__ __launch_bounds__(256) void k_gather(const unsigned char* __restrict__ hh,
                                                const int* __restrict__ rowptr,
                                                const int* __restrict__ adj,
                                                const float* __restrict__ dis,
                                                const float* __restrict__ b,
                                                const float* __restrict__ watt,
                                                void* __restrict__ outv, int n) {
  int wid = threadIdx.x >> 6;
  int lane = threadIdx.x & 63;
  int half = lane >> 5;
  int sl = lane & 31;
  int c4 = sl * 4;
  int d = blockIdx.x * 4 + wid;
  if (d >= n) return;
  int p0 = rowptr[d], p1 = rowptr[d + 1];
  float a0 = 0.f, a1 = 0.f, a2 = 0.f, a3 = 0.f;
  {  // self row: half 0 only (both halves load same 128B -> broadcastable)
    unsigned v = *(const unsigned*)&hh[(size_t)d * 128 + c4];
    float2 f01 = fp8x2_f32((unsigned short)(v & 0xFFFF));
    float2 f23 = fp8x2_f32((unsigned short)(v >> 16));
    if (half == 0) { a0 = f01.x; a1 = f01.y; a2 = f23.x; a3 = f23.y; }
  }
  for (int base = p0; base < p1; base += 64) {
    int remain = p1 - base;
    int m = remain < 64 ? remain : 64;
    int idx = (lane < m) ? adj[base + lane] : 0;
    int j = 0;
    // full batches: 8 neighbors = 4 paired loads, all valid
    for (; j + 8 <= m; j += 8) {
      int rows[4];
      unsigned v[4];
#pragma unroll
      for (int u = 0; u < 4; u++) {
        int nA = __shfl(idx, j + 2 * u);
        int nB = __shfl(idx, j + 2 * u + 1);
        rows[u] = half ? nB : nA;
      }
#pragma unroll
      for (int u = 0; u < 4; u++) v[u] = *(const unsigned*)&hh[(size_t)rows[u] * 128 + c4];
#pragma unroll
      for (int u = 0; u < 4; u++) {
        float2 f01 = fp8x2_f32((unsigned short)(v[u] & 0xFFFF));
        float2 f23 = fp8x2_f32((unsigned short)(v[u] >> 16));
        a0 += f01.x; a1 += f01.y; a2 += f23.x; a3 += f23.y;
      }
    }
    // tail: guarded pairs
    for (; j < m; j += 2) {
      int nA = __shfl(idx, j);
      int jb = j + 1 < 64 ? j + 1 : 63;
      int nB = __shfl(idx, jb);
      bool okB = (j + 1) < m;
      int row = half ? (okB ? nB : d) : nA;
      float wg = half ? (okB ? 1.f : 0.f) : 1.f;
      unsigned v = *(const unsigned*)&hh[(size_t)row * 128 + c4];
      float2 f01 = fp8x2_f32((unsigned short)(v & 0xFFFF));
      float2 f23 = fp8x2_f32((unsigned short)(v >> 16));
      a0 += wg * f01.x; a1 += wg * f01.y; a2 += wg * f23.x; a3 += wg * f23.y;
    }
  }
  // merge A-half and B-half partial sums
  a0 += __shfl_xor(a0, 32);
  a1 += __shfl_xor(a1, 32);
  a2 += __shfl_xor(a2, 32);
  a3 += __shfl_xor(a3, 32);
  float dd = dis[d];
  float x0 = fmaxf(dd * a0 + b[c4], 0.f);
  float x1v = fmaxf(dd * a1 + b[c4 + 1], 0.f);
  float x2 = fmaxf(dd * a2 + b[c4 + 2], 0.f);
  float x3 = fmaxf(dd * a3 + b[c4 + 3], 0.f);
  if (FIN == 1) {
    if (half == 0) {
      __half* o = (__half*)outv;
      __half2 h01 = __floats2half2_rn(x0, x1v);
      __half2 h23 = __floats2half2_rn(x2, x3);
      uint2 pk;
      pk.x = *(unsigned*)&h01;
      pk.y = *(unsigned*)&h23;
      *(uint2*)&o[(size_t)d * 128 + c4] = pk;
    }
  } else {
    float* o = (float*)outv;
    float p[8];
    const float* w0 = &watt[c4 * 8];
#pragma unroll
    for (int h = 0; h < 8; h++)
      p[h] = x0 * w0[h] + x1v * w0[8 + h] + x2 * w0[16 + h] + x3 * w0[24 + h];
#pragma unroll
    for (int mm = 1; mm < 32; mm <<= 1) {
#pragma unroll
      for (int h = 0; h < 8; h++) p[h] += __shfl_xor(p[h], mm);
    }
    if (lane == 0) {
      *(float4*)&o[(size_t)d * 8] = make_float4(p[0], p[1], p[2], p[3]);
      *(float4*)&o[(size_t)d * 8 + 4] = make_float4(p[4], p[5], p[6], p[7]);
    }
  }
}

// ---------------- GAT softmax pass A: denom by dst-gather (regions at NG, 2NG) ----------------
__global__ __launch_bounds__(256) void k_edgeA(const int* __restrict__ rowptr,
                                               const int* __restrict__ adj,
                                               const float* __restrict__ a_s_d,
                                               const float* __restrict__ a_s_c,
                                               const float* __restrict__ att,
                                               float* __restrict__ denom_d,
                                               float* __restrict__ denom_c) {
  int nb1 = (NG + 255) >> 8;
  int blk = blockIdx.x;
  int q = blk >= nb1;
  int d = (blk - (q ? nb1 : 0)) * 256 + threadIdx.x;
  if (d >= NG) return;
  const int* rp = rowptr + NG + (q ? NG : 0);
  const float* a_s = q ? a_s_c : a_s_d;
  float* den = q ? denom_c : denom_d;
  int p0 = rp[d], p1 = rp[d + 1];
  float4 ad4 = *(const float4*)&att[(size_t)d * 8 + q * 4];
  float4 acc = make_float4(0.f, 0.f, 0.f, 0.f);
  for (int p = p0; p < p1; p++) {
    int s = adj[p];
    float4 as4 = *(const float4*)&a_s[(size_t)s * 4];
    float v0 = as4.x + ad4.x, v1 = as4.y + ad4.y, v2 = as4.z + ad4.z, v3 = as4.w + ad4.w;
    v0 = v0 > 0.f ? v0 : 0.2f * v0;
    v1 = v1 > 0.f ? v1 : 0.2f * v1;
    v2 = v2 > 0.f ? v2 : 0.2f * v2;
    v3 = v3 > 0.f ? v3 : 0.2f * v3;
    acc.x += __expf(fminf(v0, 50.f));
    acc.y += __expf(fminf(v1, 50.f));
    acc.z += __expf(fminf(v2, 50.f));
    acc.w += __expf(fminf(v3, 50.f));
  }
  *(float4*)&den[(size_t)d * 4] = acc;
}

// ---------------- GAT softmax pass B: wsrc by src-gather (regions at 3NG, 3NG+NDR) ----------------
__global__ __launch_bounds__(256) void k_edgeB(const int* __restrict__ rowptr,
                                               const int* __restrict__ adj,
                                               const float* __restrict__ a_s_d,
                                               const float* __restrict__ a_s_c,
                                               const float* __restrict__ att,
                                               const float* __restrict__ denom_d,
                                               const float* __restrict__ denom_c,
                                               float* __restrict__ wsrc_d,
                                               float* __restrict__ wsrc_c) {
  int gw = (blockIdx.x * 256 + threadIdx.x) >> 6;
  int lane = threadIdx.x & 63;
  int q = gw >= NDR;
  int s = q ? gw - NDR : gw;
  if (q && s >= NDI) return;
  const int* rp = rowptr + 3 * NG + (q ? NDR : 0);
  const float* a_s = q ? a_s_c : a_s_d;
  const float* den = q ? denom_c : denom_d;
  float* ws = q ? wsrc_c : wsrc_d;
  int p0 = rp[s], p1 = rp[s + 1];
  float4 as4 = *(const float4*)&a_s[(size_t)s * 4];
  int attoff = q * 4;
  float4 acc = make_float4(0.f, 0.f, 0.f, 0.f);
  for (int p = p0 + lane; p < p1; p += 64) {
    int d = adj[p];
    float4 ad4 = *(const float4*)&att[(size_t)d * 8 + attoff];
    float4 dn = *(const float4*)&den[(size_t)d * 4];
    float v0 = as4.x + ad4.x, v1 = as4.y + ad4.y, v2 = as4.z + ad4.z, v3 = as4.w + ad4.w;
    v0 = v0 > 0.f ? v0 : 0.2f * v0;
    v1 = v1 > 0.f ? v1 : 0.2f * v1;
    v2 = v2 > 0.f ? v2 : 0.2f * v2;
    v3 = v3 > 0.f ? v3 : 0.2f * v3;
    acc.x += __expf(fminf(v0, 50.f)) / (dn.x + 1e-16f);
    acc.y += __expf(fminf(v1, 50.f)) / (dn.y + 1e-16f);
    acc.z += __expf(fminf(v2, 50.f)) / (dn.z + 1e-16f);
    acc.w += __expf(fminf(v3, 50.f)) / (dn.w + 1e-16f);
  }
#pragma unroll
  for (int m = 1; m < 64; m <<= 1) {
    acc.x += __shfl_xor(acc.x, m);
    acc.y += __shfl_xor(acc.y, m);
    acc.z += __shfl_xor(acc.z, m);
    acc.w += __shfl_xor(acc.w, m);
  }
  if (lane == 0) *(float4*)&ws[(size_t)s * 4] = acc;
}

// ---------------- weighted column sums (colsums live in k_build) ----------------
__global__ __launch_bounds__(512) void k_sum(const __half* __restrict__ hs_d,
                                             const float* __restrict__ wsrc_d,
                                             float* __restrict__ S_d,
                                             const __half* __restrict__ hs_c,
                                             const float* __restrict__ wsrc_c,
                                             float* __restrict__ S_c) {
  int t = threadIdx.x;
  const int nws_d = (NDR + 63) >> 6;
  int blk = blockIdx.x;
  int q = blk >= nws_d;
  const __half* hs = q ? hs_c : hs_d;
  const float* wsrc = q ? wsrc_c : wsrc_d;
  float* S = q ? S_c : S_d;
  int N = q ? NDI : NDR;
  int r0 = (q ? blk - nws_d : blk) * 64;
  int h = t >> 7;
  int r1 = min(r0 + 64, N);
  float acc = 0.f;
  for (int r = r0; r < r1; r++) acc += wsrc[r * 4 + h] * __half2float(hs[(size_t)r * 512 + t]);
  atomAddF(&S[t], acc);
}

// ---------------- final fuse ----------------
__global__ __launch_bounds__(128) void k_final(const float* __restrict__ S_d,
                                               const float* __restrict__ S_c,
                                               const float* __restrict__ bdsum,
                                               const float* __restrict__ bcsum,
                                               const float* __restrict__ bd_bias,
                                               const float* __restrict__ bc_bias,
                                               const float* __restrict__ fuse_w,
                                               const float* __restrict__ fuse_b,
                                               float* __restrict__ out) {
  __shared__ float cat[384];
  int t = threadIdx.x;
  float sd = S_d[t] + S_d[128 + t] + S_d[256 + t] + S_d[384 + t];
  float sc = S_c[t] + S_c[128 + t] + S_c[256 + t] + S_c[384 + t];
  const float inv = 1.0f / (4.0f * (float)NG);
  cat[t] = 0.5f * (sd * inv + bd_bias[t] + sc * inv + bc_bias[t]);
  cat[128 + t] = bdsum[t] * (1.0f / (float)NDR);
  cat[256 + t] = bcsum[t] * (1.0f / (float)NDI);
  __syncthreads();
  float o = fuse_b[t];
  for (int k = 0; k < 384; k++) o += cat[k] * fuse_w[k * 128 + t];
  out[t] = o;
}

// ---------------- host launch ----------------
extern "C" void kernel_launch(void* const* d_in, const int* in_sizes, int n_in,
                              void* d_out, int out_size, void* d_ws, size_t ws_size,
                              hipStream_t stream) {
  const float* gene_nodes   = (const float*)d_in[0];
  const int*   drug_edges   = (const int*)d_in[1];
  const int*   dise_edges   = (const int*)d_in[2];
  const int*   gene_edges   = (const int*)d_in[3];
  const float* gcn1_w       = (const float*)d_in[4];
  const float* gcn1_b       = (const float*)d_in[5];
  const float* gcn2_w       = (const float*)d_in[6];
  const float* gcn2_b       = (const float*)d_in[7];
  const float* drug_embed   = (const float*)d_in[8];
  const float* dise_embed   = (const float*)d_in[9];
  const float* gat_d_w      = (const float*)d_in[10];
  const float* gat_d_att_s  = (const float*)d_in[11];
  const float* gat_d_att_d  = (const float*)d_in[12];
  const float* gat_d_b      = (const float*)d_in[13];
  const float* gat_c_w      = (const float*)d_in[14];
  const float* gat_c_att_s  = (const float*)d_in[15];
  const float* gat_c_att_d  = (const float*)d_in[16];
  const float* gat_c_b      = (const float*)d_in[17];
  const float* fuse_w       = (const float*)d_in[18];
  const float* fuse_b       = (const float*)d_in[19];
  const int Ed = in_sizes[1] / 2;
  const int Ec = in_sizes[2] / 2;
  const int Eg = in_sizes[3] / 2;
  float* out = (float*)d_out;
  (void)n_in; (void)out_size; (void)ws_size;

  const int ME = Eg + 2 * (Ed + Ec);
  const int NBB = cdiv_h(ME, BCHUNK);

  // workspace layout (zero-init region first, single memset)
  char* w = (char*)d_ws;
  auto alloc = [&](size_t n) {
    char* p = w;
    w += (n + 511) & ~(size_t)511;
    return p;
  };
  char* z0 = w;
  float* S_d        = (float*)alloc(512 * 4);
  float* S_c        = (float*)alloc(512 * 4);
  float* bdsum      = (float*)alloc(512);
  float* bcsum      = (float*)alloc(512);
  int* count616     = (int*)alloc((size_t)NBUCK * 4);
  size_t zbytes = (size_t)(w - z0);
  float* denom_d    = (float*)alloc((size_t)NG * 16);
  float* denom_c    = (float*)alloc((size_t)NG * 16);
  float* wsrc_d     = (float*)alloc((size_t)NDR * 16);
  float* wsrc_c     = (float*)alloc((size_t)NDI * 16);
  float* dis        = (float*)alloc((size_t)NG * 4);
  float* watt       = (float*)alloc(128 * 8 * 4);
  float* att        = (float*)alloc((size_t)NG * 8 * 4);
  float* a_s_d      = (float*)alloc((size_t)NDR * 16);
  float* a_s_c      = (float*)alloc((size_t)NDI * 16);
  int* rowptr       = (int*)alloc((size_t)(NDOM + 1) * 4);
  int* bucketbase   = (int*)alloc((size_t)(NBUCK + 1) * 4);
  int* adj          = (int*)alloc((size_t)ME * 4);
  unsigned* pairs   = (unsigned*)alloc((size_t)NPAIR * 4);
  __half* Wt1       = (__half*)alloc((size_t)128 * 128 * 2);
  __half* Wt2       = (__half*)alloc((size_t)128 * 128 * 2);
  __half* Wtd       = (__half*)alloc((size_t)512 * 128 * 2);
  __half* Wtc       = (__half*)alloc((size_t)512 * 128 * 2);
  unsigned char* hh = (unsigned char*)alloc((size_t)NG * 128);
  __half* x1        = (__half*)alloc((size_t)NG * 128 * 2);
  __half* hs_d      = (__half*)alloc((size_t)NDR * 512 * 2);
  __half* hs_c      = (__half*)alloc((size_t)NDI * 512 * 2);

  hipMemsetAsync(z0, 0, zbytes, stream);

  // build: binH (count-based) || weight prep || watt || colsums  (one launch)
  k_build<<<NBB + 163, 256, 0, stream>>>(gene_edges, Eg, drug_edges, Ed, dise_edges, Ec,
                                         count616, pairs,
                                         gcn1_w, gcn2_w, gat_d_w, gat_c_w, gat_d_att_d, gat_c_att_d,
                                         Wt1, Wt2, Wtd, Wtc, watt,
                                         drug_embed, bdsum, dise_embed, bcsum);
  k_scan616<<<1, 256, 0, stream>>>(count616, bucketbase);
  k_placeAll<<<NBUCK, 256, 0, stream>>>(count616, bucketbase, pairs, rowptr, dis, adj);

  // GCN layer-1 GEMM || GAT source GEMMs (one launch)
  int nb1 = cdiv_h(NG, 64);
  int nbg = (cdiv_h(NDR, 64) + cdiv_h(NDI, 64)) * 4;
  k_mm1<<<nb1 + nbg, 256, 0, stream>>>(gene_nodes, Wt1, dis, hh,
                                       drug_embed, dise_embed, Wtd, Wtc,
                                       gat_d_att_s, gat_c_att_s, hs_d, hs_c, a_s_d, a_s_c);

  // GCN layer 1 aggregation (paired-row fp8 gather)
  k_gather<1><<<cdiv_h(NG, 4), 256, 0, stream>>>(hh, rowptr, adj, dis, gcn1_b, nullptr, x1, NG);

  // GCN layer 2 GEMM (f16 input, fp8 out) -> gather with att epilogue
  k_mgemm<1><<<nb1, 256, 0, stream>>>(x1, Wt2, NG, dis, hh);
  k_gather<2><<<cdiv_h(NG, 4), 256, 0, stream>>>(hh, rowptr, adj, dis, gcn2_b, watt, att, NG);

  // GAT softmax: denom by dst-gather, wsrc by src-gather
  k_edgeA<<<2 * cdiv_h(NG, 256), 256, 0, stream>>>(rowptr, adj, a_s_d, a_s_c, att, denom_d, denom_c);
  k_edgeB<<<cdiv_h((NDR + NDI) * 64, 256), 256, 0, stream>>>(rowptr, adj, a_s_d, a_s_c, att,
                                                             denom_d, denom_c, wsrc_d, wsrc_c);

  // weighted column sums
  k_sum<<<cdiv_h(NDR, 64) + cdiv_h(NDI, 64), 512, 0, stream>>>(hs_d, wsrc_d, S_d,
                                                               hs_c, wsrc_c, S_c);

  // final fuse
  k_final<<<1, 128, 0, stream>>>(S_d, S_c, bdsum, bcsum, gat_d_b, gat_c_b, fuse_w, fuse_b, out);
}

// Round 20
// 305.078 us; speedup vs baseline: 1.1325x; 1.1325x over previous
//
#include <hip/hip_runtime.h>
#include <hip/hip_fp16.h>

#define NG 100000
#define NDR 10000
#define NDI 5000
#define NDOM (3 * NG + NDR + NDI)   // 315000 combined node domain
#define NBUCK 616                   // cdiv(NDOM, 512)
#define BCHUNK 4096                 // emissions per binH block
#define EPT 16                      // emissions per thread (BCHUNK/256)

typedef _Float16 f16x8 __attribute__((ext_vector_type(8)));
typedef float f32x4 __attribute__((ext_vector_type(4)));
typedef float f32x2 __attribute__((ext_vector_type(2)));

__device__ __forceinline__ void atomAddF(float* p, float v) { unsafeAtomicAdd(p, v); }

// fp8 e4m3 (gfx950 OCP) pack/unpack
__device__ __forceinline__ float2 fp8x2_f32(unsigned short v) {
  f32x2 r = __builtin_amdgcn_cvt_pk_f32_fp8((int)v, false);
  return make_float2(r[0], r[1]);
}
__device__ __forceinline__ unsigned char f32_fp8(float v) {
  return (unsigned char)(__builtin_amdgcn_cvt_pk_fp8_f32(v, v, 0, false) & 0xFF);
}

static inline int cdiv_h(int a, int b) { return (a + b - 1) / b; }

// bucket capacity: gene/dst buckets cap 8192; drug-src cap 24576; disease-src cap 32768.
__device__ __host__ __forceinline__ int bcap(int b) {
  return b < 586 ? 8192 : (b < 606 ? 24576 : 32768);
}
__device__ __host__ __forceinline__ int bbase(int b) {
  if (b < 586) return b * 8192;
  if (b < 606) return 586 * 8192 + (b - 586) * 24576;
  return 586 * 8192 + 20 * 24576 + (b - 606) * 32768;
}
#define NPAIR (586 * 8192 + 20 * 24576 + 10 * 32768)

// ---------------- emission decode: idx in [0, Eg+2Ed+2Ec) -> (node, val) ----------------
__device__ __forceinline__ void decode(int idx, const int* __restrict__ ge, int Eg_,
                                       const int* __restrict__ de, int Ed_,
                                       const int* __restrict__ ce, int Ec_,
                                       unsigned& node, unsigned& val) {
  int B1 = Eg_, B2 = Eg_ + Ed_, B3 = Eg_ + 2 * Ed_, B4 = B3 + Ec_;
  if (idx < B1) { node = (unsigned)ge[Eg_ + idx]; val = (unsigned)ge[idx]; }
  else if (idx < B2) { int i = idx - B1; node = NG + (unsigned)de[Ed_ + i]; val = (unsigned)de[i]; }
  else if (idx < B3) { int i = idx - B2; node = 3 * NG + (unsigned)de[i]; val = (unsigned)de[Ed_ + i]; }
  else if (idx < B4) { int i = idx - B3; node = 2 * NG + (unsigned)ce[Ec_ + i]; val = (unsigned)ce[i]; }
  else { int i = idx - B4; node = 3 * NG + NDR + (unsigned)ce[i]; val = (unsigned)ce[Ec_ + i]; }
}

// ---------------- k_build: binH (count-based) || weight prep || watt || colsums ----------------
__global__ __launch_bounds__(256) void k_build(const int* __restrict__ ge, int Eg_,
                                               const int* __restrict__ de, int Ed_,
                                               const int* __restrict__ ce, int Ec_,
                                               int* __restrict__ count616,
                                               unsigned* __restrict__ pairs,
                                               const float* __restrict__ W1,
                                               const float* __restrict__ W2,
                                               const float* __restrict__ Wd,
                                               const float* __restrict__ Wc,
                                               const float* __restrict__ attd_d,
                                               const float* __restrict__ attd_c,
                                               __half* __restrict__ Wt1,
                                               __half* __restrict__ Wt2,
                                               __half* __restrict__ Wtd,
                                               __half* __restrict__ Wtc,
                                               float* __restrict__ watt,
                                               const float* __restrict__ xd,
                                               float* __restrict__ od,
                                               const float* __restrict__ xc,
                                               float* __restrict__ oc) {
  const int ME = Eg_ + 2 * (Ed_ + Ec_);
  const int NBB = (ME + BCHUNK - 1) / BCHUNK;
  int blk = blockIdx.x;
  int t = threadIdx.x;
  if (blk < NBB) {
    __shared__ int hist[NBUCK];
    for (int i = t; i < NBUCK; i += 256) hist[i] = 0;
    __syncthreads();
    int base = blk * BCHUNK;
    int cnt = min(BCHUNK, ME - base);
    unsigned nodeR[EPT], valR[EPT];
#pragma unroll
    for (int k = 0; k < EPT; k++) {
      int j = t + k * 256;
      nodeR[k] = 0xFFFFFFFFu;
      if (j < cnt) decode(base + j, ge, Eg_, de, Ed_, ce, Ec_, nodeR[k], valR[k]);
    }
#pragma unroll
    for (int k = 0; k < EPT; k++)
      if (nodeR[k] != 0xFFFFFFFFu) atomicAdd(&hist[nodeR[k] >> 9], 1);
    __syncthreads();
    for (int b = t; b < NBUCK; b += 256) {
      int h = hist[b];
      hist[b] = h ? (bbase(b) + atomicAdd(&count616[b], h)) : 0;
    }
    __syncthreads();
#pragma unroll
    for (int k = 0; k < EPT; k++) {
      if (nodeR[k] == 0xFFFFFFFFu) continue;
      unsigned b = nodeR[k] >> 9;
      int p = atomicAdd(&hist[b], 1);
      if (p < bbase(b) + bcap(b))                           // OOB guard
        pairs[p] = ((nodeR[k] - (b << 9)) << 17) | valR[k]; // local(9b) | val(17b)
    }
    return;
  }
  int fb = blk - NBB;
  if (fb < 40) {
    __shared__ float tile[64][65];
    const float* W;
    __half* Wt;
    int N, k0, n0;
    if (fb < 4) { W = W1; Wt = Wt1; N = 128; k0 = (fb >> 1) * 64; n0 = (fb & 1) * 64; }
    else if (fb < 8) { int b = fb - 4; W = W2; Wt = Wt2; N = 128; k0 = (b >> 1) * 64; n0 = (b & 1) * 64; }
    else if (fb < 24) { int b = fb - 8; W = Wd; Wt = Wtd; N = 512; k0 = (b >> 3) * 64; n0 = (b & 7) * 64; }
    else { int b = fb - 24; W = Wc; Wt = Wtc; N = 512; k0 = (b >> 3) * 64; n0 = (b & 7) * 64; }
    for (int i = t; i < 4096; i += 256) {
      int r = i >> 6, c = i & 63;
      tile[r][c] = W[(size_t)(k0 + r) * N + n0 + c];
    }
    __syncthreads();
    for (int i = t; i < 4096; i += 256) {
      int k = i & 63, n = i >> 6;
      Wt[(size_t)(n0 + n) * 128 + k0 + k] = __float2half(tile[k][n]);
    }
    return;
  }
  if (fb < 44) {
    int slot = (fb - 40) * 256 + t;
    int i = slot >> 3, s8 = slot & 7;
    const float* W = (s8 < 4) ? Wd : Wc;
    const float* A = (s8 < 4) ? attd_d : attd_c;
    int h = s8 & 3;
    float s = 0.f;
    for (int cc = 0; cc < 128; cc++) s += W[(size_t)i * 512 + h * 128 + cc] * A[h * 128 + cc];
    watt[i * 8 + s8] = s;
    return;
  }
  int cb = fb - 44;
  int q = cb >= 79;
  const float* x = q ? xc : xd;
  float* o = q ? oc : od;
  int N = q ? NDI : NDR;
  int r0 = (q ? cb - 79 : cb) * 128 + (t >> 7) * 64;
  int col = t & 127;
  int r1 = min(r0 + 64, N);
  float acc = 0.f;
  for (int r = r0; r < r1; r++) acc += x[(size_t)r * 128 + col];
  if (r0 < N) atomAddF(&o[col], acc);
}

// ---------------- scan616: exclusive prefix over bucket totals (1 block) ----------------
__global__ __launch_bounds__(256) void k_scan616(const int* __restrict__ count616,
                                                 int* __restrict__ bucketbase) {
  __shared__ int s[256];
  int t = threadIdx.x;
  int loc[3];
  int sum = 0;
#pragma unroll
  for (int k = 0; k < 3; k++) {
    int b = 3 * t + k;
    int v = (b < NBUCK) ? min(count616[b], bcap(b)) : 0;
    loc[k] = sum;
    sum += v;
  }
  s[t] = sum;
  __syncthreads();
  for (int off = 1; off < 256; off <<= 1) {
    int add = (t >= off) ? s[t - off] : 0;
    __syncthreads();
    s[t] += add;
    __syncthreads();
  }
  int excl = s[t] - sum;
#pragma unroll
  for (int k = 0; k < 3; k++) {
    int b = 3 * t + k;
    if (b < NBUCK) bucketbase[b] = excl + loc[k];
  }
}

// ---------------- placeAll: per-bucket hist -> node prefix -> rowptr+dis -> place ----------------
__global__ __launch_bounds__(256) void k_placeAll(const int* __restrict__ count616,
                                                  const int* __restrict__ bucketbase,
                                                  const unsigned* __restrict__ pairs,
                                                  int* __restrict__ rowptr,
                                                  float* __restrict__ dis,
                                                  int* __restrict__ adj) {
  __shared__ int hist[512];
  __shared__ int scan[256];
  int b = blockIdx.x;
  int n0 = b << 9;
  int n1 = min(n0 + 512, NDOM);
  int t = threadIdx.x;
  hist[t] = 0;
  hist[t + 256] = 0;
  __syncthreads();
  int base = bbase(b);
  int cnt = min(count616[b], bcap(b));
  for (int i = base + t; i < base + cnt; i += 256) atomicAdd(&hist[pairs[i] >> 17], 1);
  __syncthreads();
  int h0 = hist[2 * t], h1 = hist[2 * t + 1];
  int sum = h0 + h1;
  scan[t] = sum;
  __syncthreads();
  for (int off = 1; off < 256; off <<= 1) {
    int add = (t >= off) ? scan[t - off] : 0;
    __syncthreads();
    scan[t] += add;
    __syncthreads();
  }
  int excl = scan[t] - sum;
  int bb = bucketbase[b];
  int i0 = 2 * t, i1 = 2 * t + 1;
  int r0 = bb + excl, r1 = bb + excl + h0;
  if (n0 + i0 < n1) {
    rowptr[n0 + i0] = r0;
    if (n0 + i0 < NG) dis[n0 + i0] = rsqrtf((float)h0 + 1.0f);
  }
  if (n0 + i1 < n1) {
    rowptr[n0 + i1] = r1;
    if (n0 + i1 < NG) dis[n0 + i1] = rsqrtf((float)h1 + 1.0f);
    if (n0 + i1 == NDOM - 1) rowptr[NDOM] = r1 + h1;
  }
  if (n0 + i0 == NDOM - 1) rowptr[NDOM] = r0 + h0;
  __syncthreads();
  hist[i0] = r0;
  hist[i1] = r1;
  __syncthreads();
  for (int i = base + t; i < base + cnt; i += 256) {
    unsigned pr = pairs[i];
    int p = atomicAdd(&hist[pr >> 17], 1);
    adj[p] = (int)(pr & 0x1FFFFu);
  }
}

// ---------------- MFMA f16 GEMM body: hh[M,128] = (X[M,128] @ W) * dis[row], FP8 out ----------
template <int INF16>
__device__ __forceinline__ void mgemm_body(char* lds, int bx, const void* __restrict__ Xv,
                                           const __half* __restrict__ Wt, int M,
                                           const float* __restrict__ dis,
                                           unsigned char* __restrict__ hh) {
  char* As = lds;              // 64 x 128 f16 = 16 KB
  char* Bs = lds + 16 * 1024;  // 128 x 128 f16 = 32 KB
  const int t = threadIdx.x;
  const int row0 = bx * 64;

#pragma unroll
  for (int rep = 0; rep < 8; rep++) {
    int q = t + rep * 256;
    int r = q >> 4, c16 = (q & 15) * 16;
    uint4 v = *(const uint4*)((const char*)Wt + r * 256 + c16);
    *(uint4*)(Bs + ((r * 256 + c16) ^ ((r & 7) << 4))) = v;
  }
  if (INF16 == 0) {
    const float* X = (const float*)Xv;
#pragma unroll
    for (int rep = 0; rep < 8; rep++) {
      int q = t + rep * 256;
      int r = q >> 5, c4 = (q & 31) * 4;
      int gr = row0 + r;
      float4 xv = make_float4(0.f, 0.f, 0.f, 0.f);
      if (gr < M) xv = *(const float4*)&X[(size_t)gr * 128 + c4];
      __half2 h0 = __floats2half2_rn(xv.x, xv.y);
      __half2 h1 = __floats2half2_rn(xv.z, xv.w);
      uint2 pk;
      pk.x = *(unsigned*)&h0;
      pk.y = *(unsigned*)&h1;
      *(uint2*)(As + ((r * 256 + c4 * 2) ^ ((r & 7) << 4))) = pk;
    }
  } else {
    const __half* X = (const __half*)Xv;
#pragma unroll
    for (int rep = 0; rep < 4; rep++) {
      int q = t + rep * 256;
      int r = q >> 4, c16 = (q & 15) * 16;
      int gr = row0 + r;
      uint4 v = make_uint4(0u, 0u, 0u, 0u);
      if (gr < M) v = *(const uint4*)((const char*)X + (size_t)gr * 256 + c16);
      *(uint4*)(As + ((r * 256 + c16) ^ ((r & 7) << 4))) = v;
    }
  }
  __syncthreads();

  const int w = t >> 6, l = t & 63;
  const int lr = l & 15, lk = l >> 4;
  f32x4 acc[8] = {};
#pragma unroll
  for (int s = 0; s < 4; s++) {
    int arow = w * 16 + lr;
    f16x8 a = *(const f16x8*)(As + ((arow * 256 + lk * 16 + s * 64) ^ ((arow & 7) << 4)));
#pragma unroll
    for (int nt = 0; nt < 8; nt++) {
      int brow = nt * 16 + lr;
      f16x8 b = *(const f16x8*)(Bs + ((brow * 256 + lk * 16 + s * 64) ^ ((brow & 7) << 4)));
      acc[nt] = __builtin_amdgcn_mfma_f32_16x16x32_f16(a, b, acc[nt], 0, 0, 0);
    }
  }
  float ddv[4];
  int rowb = row0 + w * 16 + lk * 4;
#pragma unroll
  for (int j = 0; j < 4; j++) ddv[j] = (rowb + j < M) ? dis[rowb + j] : 0.f;
#pragma unroll
  for (int nt = 0; nt < 8; nt++) {
#pragma unroll
    for (int j = 0; j < 4; j++) {
      int row = rowb + j;
      if (row < M) hh[(size_t)row * 128 + nt * 16 + lr] = f32_fp8(acc[nt][j] * ddv[j]);
    }
  }
}

// ---------------- MFMA f16 GAT GEMM body (bx = row block, h = head) ----------------
__device__ __forceinline__ void mgat_body(char* lds, int bxx, int h,
                                          const float* __restrict__ Xd,
                                          const float* __restrict__ Xc,
                                          const __half* __restrict__ Wtd,
                                          const __half* __restrict__ Wtc,
                                          const float* __restrict__ attSd,
                                          const float* __restrict__ attSc,
                                          __half* __restrict__ hsd,
                                          __half* __restrict__ hsc,
                                          float* __restrict__ a_s_d,
                                          float* __restrict__ a_s_c) {
  char* As = lds;
  char* Bs = lds + 16 * 1024;
  const int t = threadIdx.x;
  const int nbd = (NDR + 63) >> 6;
  const int q = bxx >= nbd;
  const int bx = q ? bxx - nbd : bxx;
  const int M = q ? NDI : NDR;
  const float* X = q ? Xc : Xd;
  const __half* Wt = q ? Wtc : Wtd;
  const float* attS = q ? attSc : attSd;
  __half* hs = q ? hsc : hsd;
  float* a_s = q ? a_s_c : a_s_d;
  const int row0 = bx * 64;
  const __half* Wth = Wt + (size_t)h * 128 * 128;

#pragma unroll
  for (int rep = 0; rep < 8; rep++) {
    int r = (t + rep * 256) >> 4, c16 = ((t + rep * 256) & 15) * 16;
    uint4 v = *(const uint4*)((const char*)Wth + r * 256 + c16);
    *(uint4*)(Bs + ((r * 256 + c16) ^ ((r & 7) << 4))) = v;
  }
#pragma unroll
  for (int rep = 0; rep < 8; rep++) {
    int qq = t + rep * 256;
    int r = qq >> 5, c4 = (qq & 31) * 4;
    int gr = row0 + r;
    float4 xv = make_float4(0.f, 0.f, 0.f, 0.f);
    if (gr < M) xv = *(const float4*)&X[(size_t)gr * 128 + c4];
    __half2 h0 = __floats2half2_rn(xv.x, xv.y);
    __half2 h1 = __floats2half2_rn(xv.z, xv.w);
    uint2 pk;
    pk.x = *(unsigned*)&h0;
    pk.y = *(unsigned*)&h1;
    *(uint2*)(As + ((r * 256 + c4 * 2) ^ ((r & 7) << 4))) = pk;
  }
  __syncthreads();

  const int w = t >> 6, l = t & 63;
  const int lr = l & 15, lk = l >> 4;
  f32x4 acc[8] = {};
#pragma unroll
  for (int s = 0; s < 4; s++) {
    int arow = w * 16 + lr;
    f16x8 a = *(const f16x8*)(As + ((arow * 256 + lk * 16 + s * 64) ^ ((arow & 7) << 4)));
#pragma unroll
    for (int nt = 0; nt < 8; nt++) {
      int brow = nt * 16 + lr;
      f16x8 b = *(const f16x8*)(Bs + ((brow * 256 + lk * 16 + s * 64) ^ ((brow & 7) << 4)));
      acc[nt] = __builtin_amdgcn_mfma_f32_16x16x32_f16(a, b, acc[nt], 0, 0, 0);
    }
  }
  float av[8];
#pragma unroll
  for (int nt = 0; nt < 8; nt++) av[nt] = attS[h * 128 + nt * 16 + lr];

  int rowb = row0 + w * 16 + lk * 4;
  float p[4] = {0.f, 0.f, 0.f, 0.f};
#pragma unroll
  for (int nt = 0; nt < 8; nt++) {
#pragma unroll
    for (int j = 0; j < 4; j++) {
      int row = rowb + j;
      if (row < M) hs[(size_t)row * 512 + h * 128 + nt * 16 + lr] = __float2half(acc[nt][j]);
      p[j] += acc[nt][j] * av[nt];
    }
  }
#pragma unroll
  for (int m = 1; m < 16; m <<= 1) {
#pragma unroll
    for (int j = 0; j < 4; j++) p[j] += __shfl_xor(p[j], m);
  }
  if (lr == 0) {
#pragma unroll
    for (int j = 0; j < 4; j++) {
      int row = rowb + j;
      if (row < M) a_s[(size_t)row * 4 + h] = p[j];
    }
  }
}

// ---------------- fused launch: GCN layer-1 GEMM || GAT source GEMMs ----------------
__global__ __launch_bounds__(256) void k_mm1(const float* __restrict__ X1,
                                             const __half* __restrict__ Wt1,
                                             const float* __restrict__ dis,
                                             unsigned char* __restrict__ hh,
                                             const float* __restrict__ Xd,
                                             const float* __restrict__ Xc,
                                             const __half* __restrict__ Wtd,
                                             const __half* __restrict__ Wtc,
                                             const float* __restrict__ attSd,
                                             const float* __restrict__ attSc,
                                             __half* __restrict__ hsd,
                                             __half* __restrict__ hsc,
                                             float* __restrict__ a_s_d,
                                             float* __restrict__ a_s_c) {
  __shared__ __align__(16) char lds[48 * 1024];
  const int NB1 = (NG + 63) >> 6;
  if ((int)blockIdx.x < NB1) {
    mgemm_body<0>(lds, blockIdx.x, X1, Wt1, NG, dis, hh);
    return;
  }
  int r = blockIdx.x - NB1;
  mgat_body(lds, r >> 2, r & 3, Xd, Xc, Wtd, Wtc, attSd, attSc, hsd, hsc, a_s_d, a_s_c);
}

// ---------------- standalone MFMA GEMM (layer 2, f16 input, fp8 out) ----------------
template <int INF16>
__global__ __launch_bounds__(256) void k_mgemm(const void* __restrict__ Xv,
                                               const __half* __restrict__ Wt, int M,
                                               const float* __restrict__ dis,
                                               unsigned char* __restrict__ hh) {
  __shared__ __align__(16) char lds[48 * 1024];
  mgemm_body<INF16>(lds, blockIdx.x, Xv, Wt, M, dis, hh);
}

// ---------------- GCN aggregation: CSR gather, wave/dst + ILP-8, FP8 hh rows (R18 proven) ------
// FIN 1: out = x1 row f16; FIN 2: out = att row (8 scores fp32)
template <int FIN>
__global__ __launch_bounds__(256) void k_gather(const unsigned char* __restrict__ hh,
                                                const int* __restrict__ rowptr,
                                                const int* __restrict__ adj,
                                                const float* __restrict__ dis,
                                                const float* __restrict__ b,
                                                const float* __restrict__ watt,
                                                void* __restrict__ outv, int n) {
  int wid = threadIdx.x >> 6;
  int lane = threadIdx.x & 63;
  int d = blockIdx.x * 4 + wid;
  if (d >= n) return;
  int p0 = rowptr[d], p1 = rowptr[d + 1];
  int c = lane * 2;
  float2 s;
  {
    unsigned short v = *(const unsigned short*)&hh[(size_t)d * 128 + c];  // self loop
    s = fp8x2_f32(v);
  }
  for (int base = p0; base < p1; base += 64) {
    int remain = p1 - base;
    int m = remain < 64 ? remain : 64;
    int idx = (lane < m) ? adj[base + lane] : 0;
    int j = 0;
    for (; j + 8 <= m; j += 8) {
      int nb[8];
      unsigned short v[8];
#pragma unroll
      for (int u = 0; u < 8; u++) nb[u] = __shfl(idx, j + u);
#pragma unroll
      for (int u = 0; u < 8; u++) v[u] = *(const unsigned short*)&hh[(size_t)nb[u] * 128 + c];
#pragma unroll
      for (int u = 0; u < 8; u++) {
        float2 f = fp8x2_f32(v[u]);
        s.x += f.x;
        s.y += f.y;
      }
    }
    for (; j + 4 <= m; j += 4) {
      int nb[4];
      unsigned short v[4];
#pragma unroll
      for (int u = 0; u < 4; u++) nb[u] = __shfl(idx, j + u);
#pragma unroll
      for (int u = 0; u < 4; u++) v[u] = *(const unsigned short*)&hh[(size_t)nb[u] * 128 + c];
#pragma unroll
      for (int u = 0; u < 4; u++) {
        float2 f = fp8x2_f32(v[u]);
        s.x += f.x;
        s.y += f.y;
      }
    }
    for (; j < m; j++) {
      int nb = __shfl(idx, j);
      unsigned short v = *(const unsigned short*)&hh[(size_t)nb * 128 + c];
      float2 f = fp8x2_f32(v);
      s.x += f.x;
      s.y += f.y;
    }
  }
  float dd = dis[d];
  float x0 = fmaxf(dd * s.x + b[c], 0.f);
  float x1v = fmaxf(dd * s.y + b[c + 1], 0.f);
  if (FIN == 1) {
    __half* o = (__half*)outv;
    __half2 hv = __floats2half2_rn(x0, x1v);
    *(__half2*)&o[(size_t)d * 128 + c] = hv;
  } else {
    float* o = (float*)outv;
    float p[8];
    const float* w0 = &watt[c * 8];
#pragma unroll
    for (int h = 0; h < 8; h++) p[h] = x0 * w0[h] + x1v * w0[8 + h];
#pragma unroll
    for (int mm = 32; mm; mm >>= 1) {
#pragma unroll
      for (int h = 0; h < 8; h++) p[h] += __shfl_xor(p[h], mm);
    }
    if (lane == 0) {
      *(float4*)&o[(size_t)d * 8] = make_float4(p[0], p[1], p[2], p[3]);
      *(float4*)&o[(size_t)d * 8 + 4] = make_float4(p[4], p[5], p[6], p[7]);
    }
  }
}

// ---------------- GAT softmax pass A: denom by dst-gather (regions at NG, 2NG) ----------------
__global__ __launch_bounds__(256) void k_edgeA(const int* __restrict__ rowptr,
                                               const int* __restrict__ adj,
                                               const float* __restrict__ a_s_d,
                                               const float* __restrict__ a_s_c,
                                               const float* __restrict__ att,
                                               float* __restrict__ denom_d,
                                               float* __restrict__ denom_c) {
  int nb1 = (NG + 255) >> 8;
  int blk = blockIdx.x;
  int q = blk >= nb1;
  int d = (blk - (q ? nb1 : 0)) * 256 + threadIdx.x;
  if (d >= NG) return;
  const int* rp = rowptr + NG + (q ? NG : 0);
  const float* a_s = q ? a_s_c : a_s_d;
  float* den = q ? denom_c : denom_d;
  int p0 = rp[d], p1 = rp[d + 1];
  float4 ad4 = *(const float4*)&att[(size_t)d * 8 + q * 4];
  float4 acc = make_float4(0.f, 0.f, 0.f, 0.f);
  for (int p = p0; p < p1; p++) {
    int s = adj[p];
    float4 as4 = *(const float4*)&a_s[(size_t)s * 4];
    float v0 = as4.x + ad4.x, v1 = as4.y + ad4.y, v2 = as4.z + ad4.z, v3 = as4.w + ad4.w;
    v0 = v0 > 0.f ? v0 : 0.2f * v0;
    v1 = v1 > 0.f ? v1 : 0.2f * v1;
    v2 = v2 > 0.f ? v2 : 0.2f * v2;
    v3 = v3 > 0.f ? v3 : 0.2f * v3;
    acc.x += __expf(fminf(v0, 50.f));
    acc.y += __expf(fminf(v1, 50.f));
    acc.z += __expf(fminf(v2, 50.f));
    acc.w += __expf(fminf(v3, 50.f));
  }
  *(float4*)&den[(size_t)d * 4] = acc;
}

// ---------------- GAT softmax pass B: wsrc by src-gather (regions at 3NG, 3NG+NDR) ----------------
__global__ __launch_bounds__(256) void k_edgeB(const int* __restrict__ rowptr,
                                               const int* __restrict__ adj,
                                               const float* __restrict__ a_s_d,
                                               const float* __restrict__ a_s_c,
                                               const float* __restrict__ att,
                                               const float* __restrict__ denom_d,
                                               const float* __restrict__ denom_c,
                                               float* __restrict__ wsrc_d,
                                               float* __restrict__ wsrc_c) {
  int gw = (blockIdx.x * 256 + threadIdx.x) >> 6;
  int lane = threadIdx.x & 63;
  int q = gw >= NDR;
  int s = q ? gw - NDR : gw;
  if (q && s >= NDI) return;
  const int* rp = rowptr + 3 * NG + (q ? NDR : 0);
  const float* a_s = q ? a_s_c : a_s_d;
  const float* den = q ? denom_c : denom_d;
  float* ws = q ? wsrc_c : wsrc_d;
  int p0 = rp[s], p1 = rp[s + 1];
  float4 as4 = *(const float4*)&a_s[(size_t)s * 4];
  int attoff = q * 4;
  float4 acc = make_float4(0.f, 0.f, 0.f, 0.f);
  for (int p = p0 + lane; p < p1; p += 64) {
    int d = adj[p];
    float4 ad4 = *(const float4*)&att[(size_t)d * 8 + attoff];
    float4 dn = *(const float4*)&den[(size_t)d * 4];
    float v0 = as4.x + ad4.x, v1 = as4.y + ad4.y, v2 = as4.z + ad4.z, v3 = as4.w + ad4.w;
    v0 = v0 > 0.f ? v0 : 0.2f * v0;
    v1 = v1 > 0.f ? v1 : 0.2f * v1;
    v2 = v2 > 0.f ? v2 : 0.2f * v2;
    v3 = v3 > 0.f ? v3 : 0.2f * v3;
    acc.x += __expf(fminf(v0, 50.f)) / (dn.x + 1e-16f);
    acc.y += __expf(fminf(v1, 50.f)) / (dn.y + 1e-16f);
    acc.z += __expf(fminf(v2, 50.f)) / (dn.z + 1e-16f);
    acc.w += __expf(fminf(v3, 50.f)) / (dn.w + 1e-16f);
  }
#pragma unroll
  for (int m = 1; m < 64; m <<= 1) {
    acc.x += __shfl_xor(acc.x, m);
    acc.y += __shfl_xor(acc.y, m);
    acc.z += __shfl_xor(acc.z, m);
    acc.w += __shfl_xor(acc.w, m);
  }
  if (lane == 0) *(float4*)&ws[(size_t)s * 4] = acc;
}

// ---------------- weighted column sums (colsums live in k_build) ----------------
__global__ __launch_bounds__(512) void k_sum(const __half* __restrict__ hs_d,
                                             const float* __restrict__ wsrc_d,
                                             float* __restrict__ S_d,
                                             const __half* __restrict__ hs_c,
                                             const float* __restrict__ wsrc_c,
                                             float* __restrict__ S_c) {
  int t = threadIdx.x;
  const int nws_d = (NDR + 63) >> 6;
  int blk = blockIdx.x;
  int q = blk >= nws_d;
  const __half* hs = q ? hs_c : hs_d;
  const float* wsrc = q ? wsrc_c : wsrc_d;
  float* S = q ? S_c : S_d;
  int N = q ? NDI : NDR;
  int r0 = (q ? blk - nws_d : blk) * 64;
  int h = t >> 7;
  int r1 = min(r0 + 64, N);
  float acc = 0.f;
  for (int r = r0; r < r1; r++) acc += wsrc[r * 4 + h] * __half2float(hs[(size_t)r * 512 + t]);
  atomAddF(&S[t], acc);
}

// ---------------- final fuse ----------------
__global__ __launch_bounds__(128) void k_final(const float* __restrict__ S_d,
                                               const float* __restrict__ S_c,
                                               const float* __restrict__ bdsum,
                                               const float* __restrict__ bcsum,
                                               const float* __restrict__ bd_bias,
                                               const float* __restrict__ bc_bias,
                                               const float* __restrict__ fuse_w,
                                               const float* __restrict__ fuse_b,
                                               float* __restrict__ out) {
  __shared__ float cat[384];
  int t = threadIdx.x;
  float sd = S_d[t] + S_d[128 + t] + S_d[256 + t] + S_d[384 + t];
  float sc = S_c[t] + S_c[128 + t] + S_c[256 + t] + S_c[384 + t];
  const float inv = 1.0f / (4.0f * (float)NG);
  cat[t] = 0.5f * (sd * inv + bd_bias[t] + sc * inv + bc_bias[t]);
  cat[128 + t] = bdsum[t] * (1.0f / (float)NDR);
  cat[256 + t] = bcsum[t] * (1.0f / (float)NDI);
  __syncthreads();
  float o = fuse_b[t];
  for (int k = 0; k < 384; k++) o += cat[k] * fuse_w[k * 128 + t];
  out[t] = o;
}

// ---------------- host launch ----------------
extern "C" void kernel_launch(void* const* d_in, const int* in_sizes, int n_in,
                              void* d_out, int out_size, void* d_ws, size_t ws_size,
                              hipStream_t stream) {
  const float* gene_nodes   = (const float*)d_in[0];
  const int*   drug_edges   = (const int*)d_in[1];
  const int*   dise_edges   = (const int*)d_in[2];
  const int*   gene_edges   = (const int*)d_in[3];
  const float* gcn1_w       = (const float*)d_in[4];
  const float* gcn1_b       = (const float*)d_in[5];
  const float* gcn2_w       = (const float*)d_in[6];
  const float* gcn2_b       = (const float*)d_in[7];
  const float* drug_embed   = (const float*)d_in[8];
  const float* dise_embed   = (const float*)d_in[9];
  const float* gat_d_w      = (const float*)d_in[10];
  const float* gat_d_att_s  = (const float*)d_in[11];
  const float* gat_d_att_d  = (const float*)d_in[12];
  const float* gat_d_b      = (const float*)d_in[13];
  const float* gat_c_w      = (const float*)d_in[14];
  const float* gat_c_att_s  = (const float*)d_in[15];
  const float* gat_c_att_d  = (const float*)d_in[16];
  const float* gat_c_b      = (const float*)d_in[17];
  const float* fuse_w       = (const float*)d_in[18];
  const float* fuse_b       = (const float*)d_in[19];
  const int Ed = in_sizes[1] / 2;
  const int Ec = in_sizes[2] / 2;
  const int Eg = in_sizes[3] / 2;
  float* out = (float*)d_out;
  (void)n_in; (void)out_size; (void)ws_size;

  const int ME = Eg + 2 * (Ed + Ec);
  const int NBB = cdiv_h(ME, BCHUNK);

  // workspace layout (zero-init region first, single memset)
  char* w = (char*)d_ws;
  auto alloc = [&](size_t n) {
    char* p = w;
    w += (n + 511) & ~(size_t)511;
    return p;
  };
  char* z0 = w;
  float* S_d        = (float*)alloc(512 * 4);
  float* S_c        = (float*)alloc(512 * 4);
  float* bdsum      = (float*)alloc(512);
  float* bcsum      = (float*)alloc(512);
  int* count616     = (int*)alloc((size_t)NBUCK * 4);
  size_t zbytes = (size_t)(w - z0);
  float* denom_d    = (float*)alloc((size_t)NG * 16);
  float* denom_c    = (float*)alloc((size_t)NG * 16);
  float* wsrc_d     = (float*)alloc((size_t)NDR * 16);
  float* wsrc_c     = (float*)alloc((size_t)NDI * 16);
  float* dis        = (float*)alloc((size_t)NG * 4);
  float* watt       = (float*)alloc(128 * 8 * 4);
  float* att        = (float*)alloc((size_t)NG * 8 * 4);
  float* a_s_d      = (float*)alloc((size_t)NDR * 16);
  float* a_s_c      = (float*)alloc((size_t)NDI * 16);
  int* rowptr       = (int*)alloc((size_t)(NDOM + 1) * 4);
  int* bucketbase   = (int*)alloc((size_t)(NBUCK + 1) * 4);
  int* adj          = (int*)alloc((size_t)ME * 4);
  unsigned* pairs   = (unsigned*)alloc((size_t)NPAIR * 4);
  __half* Wt1       = (__half*)alloc((size_t)128 * 128 * 2);
  __half* Wt2       = (__half*)alloc((size_t)128 * 128 * 2);
  __half* Wtd       = (__half*)alloc((size_t)512 * 128 * 2);
  __half* Wtc       = (__half*)alloc((size_t)512 * 128 * 2);
  unsigned char* hh = (unsigned char*)alloc((size_t)NG * 128);
  __half* x1        = (__half*)alloc((size_t)NG * 128 * 2);
  __half* hs_d      = (__half*)alloc((size_t)NDR * 512 * 2);
  __half* hs_c      = (__half*)alloc((size_t)NDI * 512 * 2);

  hipMemsetAsync(z0, 0, zbytes, stream);

  // build: binH (count-based) || weight prep || watt || colsums  (one launch)
  k_build<<<NBB + 163, 256, 0, stream>>>(gene_edges, Eg, drug_edges, Ed, dise_edges, Ec,
                                         count616, pairs,
                                         gcn1_w, gcn2_w, gat_d_w, gat_c_w, gat_d_att_d, gat_c_att_d,
                                         Wt1, Wt2, Wtd, Wtc, watt,
                                         drug_embed, bdsum, dise_embed, bcsum);
  k_scan616<<<1, 256, 0, stream>>>(count616, bucketbase);
  k_placeAll<<<NBUCK, 256, 0, stream>>>(count616, bucketbase, pairs, rowptr, dis, adj);

  // GCN layer-1 GEMM || GAT source GEMMs (one launch)
  int nb1 = cdiv_h(NG, 64);
  int nbg = (cdiv_h(NDR, 64) + cdiv_h(NDI, 64)) * 4;
  k_mm1<<<nb1 + nbg, 256, 0, stream>>>(gene_nodes, Wt1, dis, hh,
                                       drug_embed, dise_embed, Wtd, Wtc,
                                       gat_d_att_s, gat_c_att_s, hs_d, hs_c, a_s_d, a_s_c);

  // GCN layer 1 aggregation (fp8 hh, ILP-8)
  k_gather<1><<<cdiv_h(NG, 4), 256, 0, stream>>>(hh, rowptr, adj, dis, gcn1_b, nullptr, x1, NG);

  // GCN layer 2 GEMM (f16 input, fp8 out) -> gather with att epilogue
  k_mgemm<1><<<nb1, 256, 0, stream>>>(x1, Wt2, NG, dis, hh);
  k_gather<2><<<cdiv_h(NG, 4), 256, 0, stream>>>(hh, rowptr, adj, dis, gcn2_b, watt, att, NG);

  // GAT softmax: denom by dst-gather, wsrc by src-gather
  k_edgeA<<<2 * cdiv_h(NG, 256), 256, 0, stream>>>(rowptr, adj, a_s_d, a_s_c, att, denom_d, denom_c);
  k_edgeB<<<cdiv_h((NDR + NDI) * 64, 256), 256, 0, stream>>>(rowptr, adj, a_s_d, a_s_c, att,
                                                             denom_d, denom_c, wsrc_d, wsrc_c);

  // weighted column sums
  k_sum<<<cdiv_h(NDR, 64) + cdiv_h(NDI, 64), 512, 0, stream>>>(hs_d, wsrc_d, S_d,
                                                               hs_c, wsrc_c, S_c);

  // final fuse
  k_final<<<1, 128, 0, stream>>>(S_d, S_c, bdsum, bcsum, gat_d_b, gat_c_b, fuse_w, fuse_b, out);
}